// Round 10
// baseline (487.376 us; speedup 1.0000x reference)
//
#include <hip/hip_runtime.h>
#include <hip/hip_bf16.h>
#include <math.h>

#define BATCH   2
#define SEQ     2048
#define DM      2048
#define NH      16
#define QKR     64
#define QKN     128
#define KVL     512
#define VD      128
#define QKD     192     // QKN + QKR
#define KVA_LD  640     // padded row stride of kv_a (576 -> 640 for 128-tile GEMM)
#define RMS_EPS 1.1920928955078125e-07f

typedef __bf16 bf16x8 __attribute__((ext_vector_type(8)));
typedef float  f32x4  __attribute__((ext_vector_type(4)));

// ---- async global->LDS 16B copy (wave-uniform base + lane*16 dest semantics) ----
__device__ __forceinline__ void async16(const __bf16* g, __bf16* l)
{
    __builtin_amdgcn_global_load_lds(
        (__attribute__((address_space(1))) unsigned int*)g,
        (__attribute__((address_space(3))) unsigned int*)l,
        16, 0, 0);
}

// ---- DPP row_ror lane rotate (VALU-speed cross-lane, ~4cy vs ~30cy ds_swizzle) ----
template<int CTRL>
__device__ __forceinline__ float dppf(float x)
{
    int y = __builtin_amdgcn_update_dpp(0, __builtin_bit_cast(int, x), CTRL, 0xF, 0xF, false);
    return __builtin_bit_cast(float, y);
}

// ---------------- merged prep: f32->bf16 cast (x) + 4 weight transposes ----------------
// Launch-merge round 10: 5 dispatches -> 1 (probe inter-dispatch gap cost).
// blocks: [0,8192) cast; then Wq 1536, Wkv_a 320, Wkv_b 512, Wo 1024 (total 11584).
__global__ __launch_bounds__(256) void prep_kernel(const float* __restrict__ x,
                                                   __bf16* __restrict__ xb,
                                                   const float* __restrict__ Wq,
                                                   __bf16* __restrict__ Wq_t,
                                                   const float* __restrict__ Wkv_a,
                                                   __bf16* __restrict__ Wkva_t,
                                                   const float* __restrict__ Wkv_b,
                                                   __bf16* __restrict__ Wkvb_t,
                                                   const float* __restrict__ Wo,
                                                   __bf16* __restrict__ Wo_t)
{
    __shared__ float t[64][65];
    const int tid = threadIdx.x;
    int id = blockIdx.x;
    if (id < 8192) {
        int i = (id * 256 + tid) * 4;
        float4 v = *reinterpret_cast<const float4*>(x + i);
        xb[i + 0] = (__bf16)v.x;
        xb[i + 1] = (__bf16)v.y;
        xb[i + 2] = (__bf16)v.z;
        xb[i + 3] = (__bf16)v.w;
        return;
    }
    id -= 8192;
    const float* W; __bf16* Wt; int K, N, nb;
    if (id < 1536)      {            W = Wq;    Wt = Wq_t;   K = 2048; N = 3072; nb = 48; }
    else if (id < 1856) { id -= 1536; W = Wkv_a; Wt = Wkva_t; K = 2048; N = 576;  nb = 10; }
    else if (id < 2368) { id -= 1856; W = Wkv_b; Wt = Wkvb_t; K = 512;  N = 4096; nb = 64; }
    else                { id -= 2368; W = Wo;    Wt = Wo_t;   K = 2048; N = 2048; nb = 32; }
    const int n0 = (id % nb) * 64, k0 = (id / nb) * 64;
    #pragma unroll
    for (int i = 0; i < 16; ++i) {
        int flat = i * 256 + tid;
        int kl = flat >> 6, nl = flat & 63;
        t[kl][nl] = (n0 + nl < N) ? W[(size_t)(k0 + kl) * N + n0 + nl] : 0.f;
    }
    __syncthreads();
    #pragma unroll
    for (int i = 0; i < 16; ++i) {
        int flat = i * 256 + tid;
        int nl = flat >> 6, kl = flat & 63;
        Wt[(size_t)(n0 + nl) * K + k0 + kl] = (__bf16)t[kl][nl];
    }
}

// ---------------- bf16 MFMA GEMM: C[M,N] = A[M,K] @ Bt[N,K]^T ----------------
// BK=64 + 16B-slot XOR swizzle both sides. Round 6: total 536 -> 507 us. Keep.
template<typename OT>
__global__ __launch_bounds__(256) void gemm_bf16(const __bf16* __restrict__ A,
                                                 const __bf16* __restrict__ Bt,
                                                 OT* __restrict__ C,
                                                 int K, int lda, int ldb, int ldc)
{
    __shared__ __bf16 As[128 * 64];
    __shared__ __bf16 Bs[128 * 64];
    const int tid = threadIdx.x;
    const int lane = tid & 63, wave = tid >> 6;
    const int n = lane & 15, quad = lane >> 4;
    const int row0 = blockIdx.y * 128, col0 = blockIdx.x * 128;
    const int wm = (wave >> 1) * 64, wn = (wave & 1) * 64;

    f32x4 acc[4][4];
    #pragma unroll
    for (int mi = 0; mi < 4; ++mi)
        #pragma unroll
        for (int ni = 0; ni < 4; ++ni)
            #pragma unroll
            for (int r = 0; r < 4; ++r) acc[mi][ni][r] = 0.f;

    const int srow = tid >> 3;
    const int scol8p = tid & 7;
    const __bf16* Ag[4]; const __bf16* Bg[4];
    #pragma unroll
    for (int i = 0; i < 4; ++i) {
        int row = srow + i * 32;
        int col8l = scol8p ^ (row & 7);
        Ag[i] = A  + (size_t)(row0 + row) * lda + col8l * 8;
        Bg[i] = Bt + (size_t)(col0 + row) * ldb + col8l * 8;
    }
    __bf16* Asd = As + tid * 8;   // + i*2048 elements per call (4KB)
    __bf16* Bsd = Bs + tid * 8;

    for (int k0 = 0; k0 < K; k0 += 64) {
        __syncthreads();
        #pragma unroll
        for (int i = 0; i < 4; ++i) {
            async16(Ag[i] + k0, Asd + i * 2048);
            async16(Bg[i] + k0, Bsd + i * 2048);
        }
        __syncthreads();

        #pragma unroll
        for (int kc = 0; kc < 2; ++kc) {
            bf16x8 af[4], bfr[4];
            #pragma unroll
            for (int mi = 0; mi < 4; ++mi) {
                int row = wm + mi * 16 + n;
                int slot = (kc * 4 + quad) ^ (row & 7);
                af[mi] = *reinterpret_cast<const bf16x8*>(&As[row * 64 + slot * 8]);
            }
            #pragma unroll
            for (int ni = 0; ni < 4; ++ni) {
                int row = wn + ni * 16 + n;
                int slot = (kc * 4 + quad) ^ (row & 7);
                bfr[ni] = *reinterpret_cast<const bf16x8*>(&Bs[row * 64 + slot * 8]);
            }
            #pragma unroll
            for (int mi = 0; mi < 4; ++mi)
                #pragma unroll
                for (int ni = 0; ni < 4; ++ni)
                    acc[mi][ni] = __builtin_amdgcn_mfma_f32_16x16x32_bf16(af[mi], bfr[ni], acc[mi][ni], 0, 0, 0);
        }
    }

    #pragma unroll
    for (int mi = 0; mi < 4; ++mi)
        #pragma unroll
        for (int r = 0; r < 4; ++r) {
            OT* cp = C + (size_t)(row0 + wm + mi * 16 + quad * 4 + r) * ldc + col0 + wn + n;
            #pragma unroll
            for (int ni = 0; ni < 4; ++ni)
                cp[ni * 16] = (OT)acc[mi][ni][r];
        }
}

// ---------------- merged post1: rope_q + rope_k + rmsnorm ----------------
// blocks: [0,8192) rope_q; [8192,8704) rope_k; [8704,12800) rmsnorm.
__global__ __launch_bounds__(256) void post1_kernel(__bf16* __restrict__ q,
                                                    const float* __restrict__ kva,
                                                    const float* __restrict__ w,
                                                    __bf16* __restrict__ ckv,
                                                    __bf16* __restrict__ krope)
{
    const int tid = threadIdx.x;
    int id = blockIdx.x;
    if (id < 8192) {
        // rope_q: B*S*NH*32 threads
        int idx = id * 256 + tid;
        int i = idx & 31;
        int h = (idx >> 5) & 15;
        int s = (idx >> 9) & 2047;
        int b = idx >> 20;
        float t = (float)s * __expf(-(float)(2 * i) / 64.0f * 9.210340371976184f); // ln(10000)
        float c = __cosf(t), sn = __sinf(t);
        __bf16* p = q + ((size_t)(b * SEQ + s)) * (NH * QKD) + h * QKD + QKN + 2 * i;
        float x1 = (float)p[0], x2 = (float)p[1];
        p[0] = (__bf16)(x1 * c - x2 * sn);
        p[1] = (__bf16)(x2 * c + x1 * sn);
        return;
    }
    if (id < 8704) {
        // rope_k: B*S*32 threads
        int idx = (id - 8192) * 256 + tid;
        int i = idx & 31;
        int s = (idx >> 5) & 2047;
        int b = idx >> 16;
        float t = (float)s * __expf(-(float)(2 * i) / 64.0f * 9.210340371976184f);
        float c = __cosf(t), sn = __sinf(t);
        const float* p = kva + ((size_t)(b * SEQ + s)) * KVA_LD + KVL + 2 * i;
        float x1 = p[0], x2 = p[1];
        __bf16* o = krope + ((size_t)(b * SEQ + s)) * QKR + 2 * i;
        o[0] = (__bf16)(x1 * c - x2 * sn);
        o[1] = (__bf16)(x2 * c + x1 * sn);
        return;
    }
    // rmsnorm: one block per row
    const int rid = id - 8704;
    const float* row = kva + (size_t)rid * KVA_LD;
    float v[2];
    float ss = 0.f;
    #pragma unroll
    for (int j = 0; j < 2; ++j) {
        int d = tid + j * 256;
        v[j] = row[d];
        ss += v[j] * v[j];
    }
    #pragma unroll
    for (int off = 32; off > 0; off >>= 1) ss += __shfl_down(ss, off, 64);
    __shared__ float red[4];
    if ((tid & 63) == 0) red[tid >> 6] = ss;
    __syncthreads();
    float total = red[0] + red[1] + red[2] + red[3];
    float scale = 1.0f / sqrtf(total * (1.0f / KVL) + RMS_EPS);
    #pragma unroll
    for (int j = 0; j < 2; ++j) {
        int d = tid + j * 256;
        ckv[(size_t)rid * KVL + d] = (__bf16)(v[j] * scale * w[d]);
    }
}

// ---------------- build bf16 V^T : [B,H,128,S] from bf16 kv_b ----------------
__global__ __launch_bounds__(256) void build_vt(const __bf16* __restrict__ kvb,
                                                __bf16* __restrict__ Vt)
{
    __shared__ __bf16 tile[64][136];
    const int s0 = blockIdx.x * 64, h = blockIdx.y, b = blockIdx.z;
    const int t = threadIdx.x;
    #pragma unroll
    for (int i = 0; i < 4; ++i) {
        int flat = i * 256 + t;
        int sl = flat >> 4, c8 = flat & 15;
        bf16x8 v = *reinterpret_cast<const bf16x8*>(
            &kvb[((size_t)(b * SEQ + s0 + sl)) * (NH * 256) + h * 256 + 128 + c8 * 8]);
        *reinterpret_cast<bf16x8*>(&tile[sl][c8 * 8]) = v;
    }
    __syncthreads();
    #pragma unroll
    for (int j = 0; j < 32; ++j) {
        int flat = j * 256 + t;
        int d = flat >> 6, sl = flat & 63;
        Vt[((size_t)((b * NH + h) * VD + d)) * SEQ + s0 + sl] = tile[sl][d];
    }
}

// ---------------- MFMA flash attention, wave-pair-per-strip ----------------
// Round-10 restructure: counters show LDS-throughput-bound (8300 cy/tile vs ~1000
// compute; ~75us of 114 is LDS pipe). Fix: raise K/V reuse per LDS read.
// Waves 0-1 own strip pair (rows 0-31 / 32-63), waves 2-3 own strip 31-pair.
// Each wave: 32 q-rows -> every kf/vf fragment read feeds TWO q-subtile MFMAs
// (was one). kf reads/strip-tile 96->48, vf 128->64 block-wide. VGPR-neutral
// (qfrag 12 frags = 48 regs, same as 2-strip x 6; Oa/Ol/m totals unchanged).
// Softmax: ones-column l (MFMA), DPP row_ror max, exact rescale-skip (r9: 114us).
#define LKS 200   // 192 + 8 pad (slot stride 25 = 1 mod 8: uniform bank spread)
#define LVS 72    // 64 + 8
#define LPS 72
__global__ __launch_bounds__(256, 2) void attn_mfma(const __bf16* __restrict__ qb,
                                                    const __bf16* __restrict__ kvb,
                                                    const __bf16* __restrict__ krope,
                                                    const __bf16* __restrict__ Vt,
                                                    __bf16* __restrict__ ob)
{
    __shared__ __bf16 Ks[64 * LKS];      // 25600 B
    __shared__ __bf16 Vs[128 * LVS];     // 18432 B
    __shared__ __bf16 Ps[8 * 16 * LPS];  // 18432 B (4 waves x 32 rows)  total 62464 B
    const int tid = threadIdx.x;
    const int wave = tid >> 6, lane = tid & 63;
    const int n = lane & 15, quad = lane >> 4;
    const int pair = blockIdx.x, h = blockIdx.y, b = blockIdx.z;
    const int bh = b * NH + h;
    const float scale = 0.07216878364870323f;   // 1/sqrt(192)
    const int qs1 = 31 - pair;
    const int mystrip = (wave >> 1) ? qs1 : pair;
    const int whalf = wave & 1;                 // which 32-row half of my strip
    const int ntmax = qs1 + 1;

    const __bf16 one_bf = (__bf16)1.0f;
    const bf16x8 onesf = {one_bf, one_bf, one_bf, one_bf, one_bf, one_bf, one_bf, one_bf};

    // Q fragments: 2 q-subtiles of MY strip (A-layout: m=n, k=quad*8+j)
    bf16x8 qfrag[2][6];
    #pragma unroll
    for (int qt = 0; qt < 2; ++qt) {
        const int qrow = mystrip * 64 + whalf * 32 + qt * 16 + n;
        const __bf16* qp = qb + ((size_t)(b * SEQ + qrow)) * (NH * QKD) + h * QKD + quad * 8;
        #pragma unroll
        for (int c = 0; c < 6; ++c)
            qfrag[qt][c] = *reinterpret_cast<const bf16x8*>(qp + c * 32);
    }

    f32x4 Oa[2][8];
    f32x4 Ol[2];
    float m_i[2][4];
    #pragma unroll
    for (int qt = 0; qt < 2; ++qt) {
        #pragma unroll
        for (int i = 0; i < 8; ++i)
            #pragma unroll
            for (int r = 0; r < 4; ++r) Oa[qt][i][r] = 0.f;
        #pragma unroll
        for (int r = 0; r < 4; ++r) { Ol[qt][r] = 0.f; m_i[qt][r] = -1e30f; }
    }

    // per-thread staging coordinates (block-cooperative, unchanged)
    int kkey[6], kc8[6];
    #pragma unroll
    for (int i = 0; i < 6; ++i) {
        int flat = i * 256 + tid;
        kkey[i] = flat / 24; kc8[i] = flat % 24;
    }
    const int vd = tid >> 3, vc8 = tid & 7;     // flat = i*256+tid -> d = vd + i*32

    const __bf16* Vg = Vt + (size_t)bh * VD * SEQ;

    bf16x8 kpre[6], vpre[4];
    // prefetch tile 0
    {
        const int k0 = 0;
        #pragma unroll
        for (int i = 0; i < 6; ++i) {
            const __bf16* src = (kc8[i] < 16)
                ? kvb + ((size_t)(b * SEQ + k0 + kkey[i])) * (NH * 256) + h * 256 + kc8[i] * 8
                : krope + ((size_t)(b * SEQ + k0 + kkey[i])) * QKR + (kc8[i] - 16) * 8;
            kpre[i] = *reinterpret_cast<const bf16x8*>(src);
        }
        #pragma unroll
        for (int i = 0; i < 4; ++i)
            vpre[i] = *reinterpret_cast<const bf16x8*>(Vg + (size_t)(vd + i * 32) * SEQ + k0 + vc8 * 8);
    }

    for (int kt = 0; kt < ntmax; ++kt) {
        __syncthreads();   // previous iteration's compute done; Ks/Vs safe to overwrite
        #pragma unroll
        for (int i = 0; i < 6; ++i)
            *reinterpret_cast<bf16x8*>(&Ks[kkey[i] * LKS + kc8[i] * 8]) = kpre[i];
        #pragma unroll
        for (int i = 0; i < 4; ++i)
            *reinterpret_cast<bf16x8*>(&Vs[(vd + i * 32) * LVS + vc8 * 8]) = vpre[i];
        __syncthreads();

        // prefetch next tile into registers (overlaps with compute below)
        if (kt + 1 < ntmax) {
            const int k0n = (kt + 1) * 64;
            #pragma unroll
            for (int i = 0; i < 6; ++i) {
                const __bf16* src = (kc8[i] < 16)
                    ? kvb + ((size_t)(b * SEQ + k0n + kkey[i])) * (NH * 256) + h * 256 + kc8[i] * 8
                    : krope + ((size_t)(b * SEQ + k0n + kkey[i])) * QKR + (kc8[i] - 16) * 8;
                kpre[i] = *reinterpret_cast<const bf16x8*>(src);
            }
            #pragma unroll
            for (int i = 0; i < 4; ++i)
                vpre[i] = *reinterpret_cast<const bf16x8*>(Vg + (size_t)(vd + i * 32) * SEQ + k0n + vc8 * 8);
        }

        if (kt <= mystrip) {   // wave-uniform
            const int k0 = kt * 64;

            // scores: S[32q x 64k]; each kf read feeds both q-subtiles
            f32x4 sacc[2][4];
            #pragma unroll
            for (int qt = 0; qt < 2; ++qt)
                #pragma unroll
                for (int t = 0; t < 4; ++t)
                    #pragma unroll
                    for (int r = 0; r < 4; ++r) sacc[qt][t][r] = 0.f;
            #pragma unroll
            for (int t = 0; t < 4; ++t)
                #pragma unroll
                for (int c = 0; c < 6; ++c) {
                    bf16x8 kf = *reinterpret_cast<const bf16x8*>(&Ks[(t * 16 + n) * LKS + c * 32 + quad * 8]);
                    sacc[0][t] = __builtin_amdgcn_mfma_f32_16x16x32_bf16(qfrag[0][c], kf, sacc[0][t], 0, 0, 0);
                    sacc[1][t] = __builtin_amdgcn_mfma_f32_16x16x32_bf16(qfrag[1][c], kf, sacc[1][t], 0, 0, 0);
                }

            const bool diag = (kt == mystrip);
            #pragma unroll
            for (int qt = 0; qt < 2; ++qt) {
                const int qg = mystrip * 64 + whalf * 32 + qt * 16 + quad * 4;
                float mloc[4];
                #pragma unroll
                for (int r = 0; r < 4; ++r) mloc[r] = -1e30f;
                #pragma unroll
                for (int t = 0; t < 4; ++t) {
                    int key = k0 + t * 16 + n;
                    #pragma unroll
                    for (int r = 0; r < 4; ++r) {
                        float sv = sacc[qt][t][r] * scale;
                        if (diag) sv = (key <= qg + r) ? sv : -1e30f;
                        sacc[qt][t][r] = sv;
                        mloc[r] = fmaxf(mloc[r], sv);
                    }
                }
                // max over the 16-lane row via DPP row_ror butterfly (VALU, no LDS pipe)
                #pragma unroll
                for (int r = 0; r < 4; ++r) mloc[r] = fmaxf(mloc[r], dppf<0x121>(mloc[r]));
                #pragma unroll
                for (int r = 0; r < 4; ++r) mloc[r] = fmaxf(mloc[r], dppf<0x122>(mloc[r]));
                #pragma unroll
                for (int r = 0; r < 4; ++r) mloc[r] = fmaxf(mloc[r], dppf<0x124>(mloc[r]));
                #pragma unroll
                for (int r = 0; r < 4; ++r) mloc[r] = fmaxf(mloc[r], dppf<0x128>(mloc[r]));

                // exact rescale-skip: alpha==1 bitwise when max didn't grow
                float mnew[4];
                #pragma unroll
                for (int r = 0; r < 4; ++r) mnew[r] = fmaxf(m_i[qt][r], mloc[r]);
                int grow = __any((mnew[0] > m_i[qt][0]) || (mnew[1] > m_i[qt][1]) ||
                                 (mnew[2] > m_i[qt][2]) || (mnew[3] > m_i[qt][3]));
                if (grow) {
                    float alpha[4];
                    #pragma unroll
                    for (int r = 0; r < 4; ++r) alpha[r] = __expf(m_i[qt][r] - mnew[r]);
                    #pragma unroll
                    for (int i = 0; i < 8; ++i)
                        #pragma unroll
                        for (int r = 0; r < 4; ++r) Oa[qt][i][r] *= alpha[r];
                    #pragma unroll
                    for (int r = 0; r < 4; ++r) Ol[qt][r] *= alpha[r];
                }
                #pragma unroll
                for (int r = 0; r < 4; ++r) m_i[qt][r] = mnew[r];

                #pragma unroll
                for (int t = 0; t < 4; ++t)
                    #pragma unroll
                    for (int r = 0; r < 4; ++r) {
                        float p = __expf(sacc[qt][t][r] - m_i[qt][r]);
                        Ps[wave * 32 * LPS + (qt * 16 + quad * 4 + r) * LPS + t * 16 + n] = (__bf16)p;
                    }
            }

            // drain P writes (per-wave region; in-wave ordering only)
            __asm__ volatile("s_waitcnt lgkmcnt(0)" ::: "memory");

            // PV: O[32q x 128vd] += P[32x64] * V[64x128]; l += P @ ones
            // each vf read feeds both q-subtiles
            #pragma unroll
            for (int kc = 0; kc < 2; ++kc) {
                bf16x8 pf0 = *reinterpret_cast<const bf16x8*>(&Ps[wave * 32 * LPS + n * LPS + kc * 32 + quad * 8]);
                bf16x8 pf1 = *reinterpret_cast<const bf16x8*>(&Ps[wave * 32 * LPS + (16 + n) * LPS + kc * 32 + quad * 8]);
                Ol[0] = __builtin_amdgcn_mfma_f32_16x16x32_bf16(pf0, onesf, Ol[0], 0, 0, 0);
                Ol[1] = __builtin_amdgcn_mfma_f32_16x16x32_bf16(pf1, onesf, Ol[1], 0, 0, 0);
                #pragma unroll
                for (int vt = 0; vt < 8; ++vt) {
                    bf16x8 vf = *reinterpret_cast<const bf16x8*>(&Vs[(vt * 16 + n) * LVS + kc * 32 + quad * 8]);
                    Oa[0][vt] = __builtin_amdgcn_mfma_f32_16x16x32_bf16(pf0, vf, Oa[0][vt], 0, 0, 0);
                    Oa[1][vt] = __builtin_amdgcn_mfma_f32_16x16x32_bf16(pf1, vf, Oa[1][vt], 0, 0, 0);
                }
            }
        }
    }

    // epilogue: 2 q-subtiles of my strip
    #pragma unroll
    for (int qt = 0; qt < 2; ++qt)
        #pragma unroll
        for (int r = 0; r < 4; ++r) {
            float inv = 1.0f / Ol[qt][r];
            int row = mystrip * 64 + whalf * 32 + qt * 16 + quad * 4 + r;
            __bf16* op = ob + ((size_t)(b * SEQ + row)) * (NH * VD) + h * VD;
            #pragma unroll
            for (int vt = 0; vt < 8; ++vt)
                op[vt * 16 + n] = (__bf16)(Oa[qt][vt][r] * inv);
        }
}

extern "C" void kernel_launch(void* const* d_in, const int* in_sizes, int n_in,
                              void* d_out, int out_size, void* d_ws, size_t ws_size,
                              hipStream_t stream)
{
    const float* x         = (const float*)d_in[0];
    const float* Wq        = (const float*)d_in[1];
    const float* Wkv_a     = (const float*)d_in[2];
    const float* kv_norm_w = (const float*)d_in[3];
    const float* Wkv_b     = (const float*)d_in[4];
    const float* Wo        = (const float*)d_in[5];
    float* out = (float*)d_out;

    // workspace layout (f32-unit offsets); aliasing noted
    float* ws = (float*)d_ws;
    __bf16* q_bf   = (__bf16*)ws;                              // 12,582,912 bf16
    float*  kv_a   = ws + 6291456;                             // 4096x640 f32
    __bf16* kv_b   = (__bf16*)(ws + 8912896);                  // 16,777,216 bf16
    float*  r3     = ws + 17301504;                            // xb then Vt (alias)
    __bf16* xb     = (__bf16*)r3;                              // 8,388,608 bf16
    __bf16* Vt     = (__bf16*)r3;                              // 8,388,608 bf16
    float*  r4     = ws + 21495808;                            // weights then attn_o (alias)
    __bf16* Wq_t   = (__bf16*)r4;                              // 6,291,456 bf16
    __bf16* Wkva_t = (__bf16*)(r4 + 3145728);                  // 1,310,720 bf16
    __bf16* Wkvb_t = (__bf16*)(r4 + 3801088);                  // 2,097,152 bf16
    __bf16* attn_o = (__bf16*)r4;                              // 8,388,608 bf16 (weights dead)
    __bf16* Wo_t   = (__bf16*)(ws + 27787264);                 // 4,194,304 bf16
    __bf16* c_kv_n = (__bf16*)(ws + 29884416);                 // 2,097,152 bf16
    __bf16* krope  = (__bf16*)(ws + 30932992);                 //   262,144 bf16
    // total ≈ 124.3 MB

    const int M = BATCH * SEQ;   // 4096
    dim3 blk(256);

    prep_kernel<<<11584, blk, 0, stream>>>(x, xb, Wq, Wq_t, Wkv_a, Wkva_t,
                                           Wkv_b, Wkvb_t, Wo, Wo_t);

    gemm_bf16<__bf16><<<dim3(3072 / 128, M / 128), blk, 0, stream>>>(xb, Wq_t, q_bf, DM, DM, DM, NH * QKD);
    gemm_bf16<float><<<dim3(640 / 128, M / 128), blk, 0, stream>>>(xb, Wkva_t, kv_a, DM, DM, DM, KVA_LD);

    post1_kernel<<<12800, blk, 0, stream>>>(q_bf, kv_a, kv_norm_w, c_kv_n, krope);

    gemm_bf16<__bf16><<<dim3(4096 / 128, M / 128), blk, 0, stream>>>(c_kv_n, Wkvb_t, kv_b, KVL, KVL, KVL, NH * 256);

    build_vt<<<dim3(SEQ / 64, NH, BATCH), blk, 0, stream>>>(kv_b, Vt);

    attn_mfma<<<dim3(16, NH, BATCH), blk, 0, stream>>>(q_bf, kv_b, krope, Vt, attn_o);

    gemm_bf16<float><<<dim3(2048 / 128, M / 128), blk, 0, stream>>>(attn_o, Wo_t, out, NH * VD, NH * VD, NH * VD, DM);
}